// Round 6
// baseline (182.262 us; speedup 1.0000x reference)
//
#include <hip/hip_runtime.h>

typedef unsigned short u16;
typedef __attribute__((ext_vector_type(8))) short bf16x8;   // MFMA A/B frag (8 bf16)
typedef __attribute__((ext_vector_type(4))) float f32x4;    // 16x16 C/D frag
typedef __attribute__((ext_vector_type(16))) float f32x16;  // 32x32 C/D frag

#define MFMA16(a, b, c) __builtin_amdgcn_mfma_f32_16x16x32_bf16((a), (b), (c), 0, 0, 0)
#define MFMA32(a, b, c) __builtin_amdgcn_mfma_f32_32x32x16_bf16((a), (b), (c), 0, 0, 0)

// async global->LDS, 16B per lane; LDS dest = wave-uniform base + lane*16
__device__ __forceinline__ void gll16(const void* g, void* l) {
    __builtin_amdgcn_global_load_lds(
        (const __attribute__((address_space(1))) unsigned int*)g,
        (__attribute__((address_space(3))) unsigned int*)l, 16, 0, 0);
}

__device__ __forceinline__ u16 f2b(float f) {   // f32 -> bf16 RNE (scalar)
    unsigned int u = __float_as_uint(f);
    u += 0x7fffu + ((u >> 16) & 1u);
    return (u16)(u >> 16);
}

// packed bf16x2 via HW converter (RNE): lo=cvt(a), hi=cvt(b).
__device__ __forceinline__ unsigned int pkcvt(float a, float b) {
    unsigned int r;
    asm("v_cvt_pk_bf16_f32 %0, %1, %2" : "=v"(r) : "v"(a), "v"(b));
    return r;
}

// ---------------------------------------------------------------- one cast kernel
__global__ __launch_bounds__(256) void cast_all(const float* __restrict__ x,
                                                const float* __restrict__ w0,
                                                const float* __restrict__ w1,
                                                const float* __restrict__ w2,
                                                const float* __restrict__ w3,
                                                u16* __restrict__ xb,
                                                u16* __restrict__ wb) {
    const int bid = blockIdx.x;
    const float* s; u16* d; int off;
    if (bid < 2048) { s = x; d = xb; off = bid; }
    else {
        const int wi = (bid - 2048) >> 9;
        s = (wi == 0) ? w0 : (wi == 1) ? w1 : (wi == 2) ? w2 : w3;
        d = wb + (size_t)wi * 1048576;
        off = (bid - 2048) & 511;
    }
    const int i = (off * 256 + threadIdx.x) * 8;
    float4 a = *(const float4*)(s + i);
    float4 b = *(const float4*)(s + i + 4);
    *(uint4*)(d + i) = make_uint4(pkcvt(a.x, a.y), pkcvt(a.z, a.w),
                                  pkcvt(b.x, b.y), pkcvt(b.z, b.w));
}

// ---------------------------------------------------------------- GEMM, dbuf K-loop
// (unchanged from R4 — proven: QKV 128^2 @3/CU, o-proj 128x64 @2/CU)
template <int BM, int BN, int MODE, int SLOTS>
__global__ __launch_bounds__(256) void gemm_bt(const u16* __restrict__ A,
                                               const u16* __restrict__ W,
                                               void* __restrict__ Yv,
                                               u16* __restrict__ vT,
                                               int K, int ldY) {
    constexpr int MI = BM / 32, NJ = BN / 32;
    constexpr int ACH = BM / 16;
    constexpr int NPW = (BM + BN) / 64;
    __shared__ u16 As[2][SLOTS][BM * 32];
    __shared__ u16 Bs[2][SLOTS][BN * 32];
    const int t = threadIdx.x, w = t >> 6, lane = t & 63;
    const int quad = lane >> 4, m16 = lane & 15;
    const int wr = (w >> 1) * (BM / 2), wc = (w & 1) * (BN / 2);
    const int row0 = blockIdx.x * BM, col0 = blockIdx.y * BN;
    const int srow = lane >> 2, scol = (lane & 3) * 8;

    auto stage = [&](int buf, int slot, int k0) {
#pragma unroll
        for (int cc = 0; cc < NPW; ++cc) {
            const int c = w * NPW + cc;
            if (c < ACH)
                gll16(A + (size_t)(row0 + c * 16 + srow) * K + k0 + scol,
                      &As[buf][slot][c * 512]);
            else
                gll16(W + (size_t)(col0 + (c - ACH) * 16 + srow) * K + k0 + scol,
                      &Bs[buf][slot][(c - ACH) * 512]);
        }
    };

    f32x4 acc[MI][NJ];
#pragma unroll
    for (int i = 0; i < MI; ++i)
#pragma unroll
        for (int j = 0; j < NJ; ++j) acc[i][j] = (f32x4){0.f, 0.f, 0.f, 0.f};

    auto compute_tile = [&](int buf, int slot) {
        bf16x8 af[MI], bf[NJ];
#pragma unroll
        for (int i = 0; i < MI; ++i)
            af[i] = *(const bf16x8*)&As[buf][slot][(wr + i * 16 + m16) * 32 + quad * 8];
#pragma unroll
        for (int j = 0; j < NJ; ++j)
            bf[j] = *(const bf16x8*)&Bs[buf][slot][(wc + j * 16 + m16) * 32 + quad * 8];
#pragma unroll
        for (int i = 0; i < MI; ++i)
#pragma unroll
            for (int j = 0; j < NJ; ++j) acc[i][j] = MFMA16(af[i], bf[j], acc[i][j]);
    };

#pragma unroll
    for (int s = 0; s < SLOTS; ++s) stage(0, s, s * 32);
    const int ngroups = K / (32 * SLOTS);
    for (int g = 0; g < ngroups; ++g) {
        const int buf = g & 1;
        __syncthreads();
        const int kn = (g + 1) * SLOTS * 32;
        if (kn < K) {
#pragma unroll
            for (int s = 0; s < SLOTS; ++s) stage(buf ^ 1, s, kn + s * 32);
        }
#pragma unroll
        for (int s = 0; s < SLOTS; ++s) compute_tile(buf, s);
    }
    if constexpr (MODE == 0) {
#pragma unroll
        for (int i = 0; i < MI; ++i)
#pragma unroll
            for (int j = 0; j < NJ; ++j)
#pragma unroll
                for (int r = 0; r < 4; ++r)
                    ((float*)Yv)[(size_t)(row0 + wr + i * 16 + quad * 4 + r) * ldY +
                                 col0 + wc + j * 16 + m16] = acc[i][j][r];
    } else {
        if (col0 < 2048) {
            u16* qk = (u16*)Yv;
#pragma unroll
            for (int i = 0; i < MI; ++i)
#pragma unroll
                for (int j = 0; j < NJ; ++j)
#pragma unroll
                    for (int r = 0; r < 4; ++r)
                        qk[(size_t)(row0 + wr + i * 16 + quad * 4 + r) * 2048 +
                           col0 + wc + j * 16 + m16] = f2b(acc[i][j][r]);
        } else {
#pragma unroll
            for (int i = 0; i < MI; ++i) {
                const int rbase = row0 + wr + i * 16;
                const int bb = rbase >> 10;
                const int tok0 = (rbase & 1023) + quad * 4;
#pragma unroll
                for (int j = 0; j < NJ; ++j) {
                    const int vTrow = bb * 1024 + (col0 + wc + j * 16 + m16 - 2048);
                    *(uint2*)(vT + (size_t)vTrow * 1024 + tok0) =
                        make_uint2(pkcvt(acc[i][j][0], acc[i][j][1]),
                                   pkcvt(acc[i][j][2], acc[i][j][3]));
                }
            }
        }
    }
}

// ---------------------------------------------------------------- based attention, 32x32
// R6 rewrite: 32x32x16 MFMA, S kept fully in registers (no Ss LDS round-trip).
// Each wave owns ONE 32-row q-tile j; block = 4 waves with j in {p,31-p,8+p,23-p}
// (uniform 34 compute-units/block). K/V staged in LDS exactly as before (gll16,
// dbuf). QK^T: D-layout puts q=lane&31 LANE-LOCAL -> S->PV A-operand needs only a
// lane^32 half-exchange (16 pkcvt + 16 shfl_xor), T12 pattern. den = one extra
// MFMA column with B=ones (same layout as num). LDS 32KB (was 48).
__global__ __launch_bounds__(256) void based_attn32(const u16* __restrict__ qkm,
                                                    const u16* __restrict__ vT,
                                                    u16* __restrict__ o) {
    __shared__ u16 ks[2][2][64][32];   // [buf][dblk][key][32 dims]  16KB
    __shared__ u16 vs[2][2][64][32];   // [buf][kblk][vdim][32 keys] 16KB

    const int t = threadIdx.x, w = t >> 6, lane = t & 63;
    const int m = lane & 31, h = lane >> 5;
    const int p = blockIdx.x, hh = blockIdx.y, b = blockIdx.z;
    // wave -> q-tile (32 rows): pairs (p,31-p),(8+p,23-p): uniform block work
    const int j = (w == 0) ? p : (w == 1) ? (31 - p) : (w == 2) ? (8 + p) : (23 - p);
    const int ktmax_w = j >> 1;              // this wave's last key-tile
    const int KTMAX = (31 - p) >> 1;         // block staging bound (max over waves)
    const int srow = lane >> 2, s8 = (lane & 3) * 8;

    const size_t qbase = (size_t)b * 1024 * 2048 + hh * 64;
    const size_t kbase = qbase + 1024;
    const size_t vbase = ((size_t)b * 1024 + hh * 64) * 1024;

    // Q frags: lane supplies q-row (col) = m, dims kd*16 + h*8 .. +7
    bf16x8 qf[4];
#pragma unroll
    for (int kd = 0; kd < 4; ++kd)
        qf[kd] = *(const bf16x8*)(qkm + qbase + (size_t)(j * 32 + m) * 2048 +
                                  kd * 16 + h * 8);

    auto stage_tile = [&](int kt, int buf) {
#pragma unroll
        for (int cc = 0; cc < 2; ++cc) {
            const int c = w * 2 + cc;
            const int blk = c >> 2, rc = c & 3;
            gll16(qkm + kbase + (size_t)(kt * 64 + rc * 16 + srow) * 2048 + blk * 32 + s8,
                  &ks[buf][blk][rc * 16][0]);
            gll16(vT + vbase + (size_t)(rc * 16 + srow) * 1024 + kt * 64 + blk * 32 + s8,
                  &vs[buf][blk][rc * 16][0]);
        }
    };

    bf16x8 ones;
#pragma unroll
    for (int e = 0; e < 8; ++e) ones[e] = (short)0x3F80;

    f32x16 num0, num1, den;
#pragma unroll
    for (int e = 0; e < 16; ++e) { num0[e] = 0.f; num1[e] = 0.f; den[e] = 0.f; }

    auto compute = [&](int buf, int kt) {
        const bool diag = (kt == ktmax_w);
        const bool odd = (j & 1) != 0;
        const bool do1 = (!diag) || odd;     // key-chunk 1 has any live scores?

        // ---- QK^T: S^T chunks [32 keys][32 q], K-dim 64 in 4 steps of 16
        f32x16 s0, s1;
#pragma unroll
        for (int e = 0; e < 16; ++e) { s0[e] = 0.f; s1[e] = 0.f; }
#pragma unroll
        for (int kd = 0; kd < 4; ++kd) {
            bf16x8 k0 = *(const bf16x8*)&ks[buf][kd >> 1][m][(kd & 1) * 16 + h * 8];
            s0 = MFMA32(k0, qf[kd], s0);
            if (do1) {
                bf16x8 k1 = *(const bf16x8*)&ks[buf][kd >> 1][32 + m][(kd & 1) * 16 + h * 8];
                s1 = MFMA32(k1, qf[kd], s1);
            }
        }

        // ---- transform + causal mask (register-resident)
        // D layout: col(q)=lane&31, row(key_local)=(r&3)+8*(r>>2)+4*h
        float sc0[16], sc1[16];
#pragma unroll
        for (int r = 0; r < 16; ++r) {
            const int kl = (r & 3) + 8 * (r >> 2) + 4 * h;
            float u0 = fmaf(s0[r], 0.125f, 1.0f);
            float v0 = fmaf(u0 * 0.5f, u0, 0.5f);
            if (diag && !odd && kl > m) v0 = 0.f;
            sc0[r] = v0;
            float v1 = 0.f;
            if (do1) {
                float u1 = fmaf(s1[r], 0.125f, 1.0f);
                v1 = fmaf(u1 * 0.5f, u1, 0.5f);
                if (diag && odd && kl > m) v1 = 0.f;
            }
            sc1[r] = v1;
        }

        // ---- pack to bf16 + half-exchange (lane <-> lane^32)
        unsigned o0[8], o1[8], p0[8], p1[8];
#pragma unroll
        for (int i = 0; i < 8; ++i) {
            o0[i] = pkcvt(sc0[2 * i], sc0[2 * i + 1]);
            o1[i] = pkcvt(sc1[2 * i], sc1[2 * i + 1]);
        }
#pragma unroll
        for (int i = 0; i < 8; ++i) {
            p0[i] = __shfl_xor(o0[i], 32);
            p1[i] = __shfl_xor(o1[i], 32);
        }

        // ---- PV + den: A = S[q][k] (row=q=lane&31), B = V[k][vd] (col=vd)
#pragma unroll
        for (int ksi = 0; ksi < 4; ++ksi) {
            const int bx = (ksi & 1) * 4 + 2 * h;     // pk index base
            union { unsigned u[4]; bf16x8 v; } af;
            if (ksi < 2) {
                af.u[0] = h ? p0[bx] : o0[bx];
                af.u[1] = h ? p0[bx + 1] : o0[bx + 1];
                af.u[2] = h ? o0[bx] : p0[bx];
                af.u[3] = h ? o0[bx + 1] : p0[bx + 1];
            } else {
                af.u[0] = h ? p1[bx] : o1[bx];
                af.u[1] = h ? p1[bx + 1] : o1[bx + 1];
                af.u[2] = h ? o1[bx] : p1[bx];
                af.u[3] = h ? o1[bx + 1] : p1[bx + 1];
            }
            bf16x8 v0 = *(const bf16x8*)&vs[buf][ksi >> 1][m][(ksi & 1) * 16 + h * 8];
            bf16x8 v1 = *(const bf16x8*)&vs[buf][ksi >> 1][32 + m][(ksi & 1) * 16 + h * 8];
            num0 = MFMA32(af.v, v0, num0);
            num1 = MFMA32(af.v, v1, num1);
            den  = MFMA32(af.v, ones, den);
        }
    };

    stage_tile(0, 0);
    for (int kt = 0; kt <= KTMAX; ++kt) {
        const int buf = kt & 1;
        __syncthreads();                      // tile kt landed; buf^1 free
        if (kt < KTMAX) stage_tile(kt + 1, buf ^ 1);
        if (kt <= ktmax_w) compute(buf, kt);
    }

    // ---- epilogue: o[tok][hh*64 + vd] = num/den
#pragma unroll
    for (int r = 0; r < 16; ++r) {
        const int q = (r & 3) + 8 * (r >> 2) + 4 * h;
        const float inv = 1.0f / den[r];
        const size_t tok = (size_t)(b * 1024 + j * 32 + q);
        o[tok * 1024 + hh * 64 + m]      = f2b(num0[r] * inv);
        o[tok * 1024 + hh * 64 + 32 + m] = f2b(num1[r] * inv);
    }
}

// ---------------------------------------------------------------- launch
extern "C" void kernel_launch(void* const* d_in, const int* in_sizes, int n_in,
                              void* d_out, int out_size, void* d_ws, size_t ws_size,
                              hipStream_t stream) {
    const float* x  = (const float*)d_in[0];
    const float* Wq = (const float*)d_in[1];
    const float* Wk = (const float*)d_in[2];
    const float* Wv = (const float*)d_in[3];
    const float* Wo = (const float*)d_in[4];
    float* out = (float*)d_out;

    const size_t MEL = 4096ull * 1024ull;        // 4M elements
    u16* xb   = (u16*)d_ws;                      // 4096 x 1024
    u16* Wqkv = xb + MEL;                        // 3072 x 1024 (Wq|Wk|Wv rows)
    u16* Wob  = Wqkv + 3ull * 1024 * 1024;       // 1024 x 1024
    u16* qk   = Wob + 1024ull * 1024;            // 4096 x 2048 (q|k)
    u16* vT   = qk + 2ull * MEL;                 // [b*1024+h*64+vd][1024 tokens]
    u16* o    = vT + MEL;                        // 4096 x 1024

    cast_all<<<4096, 256, 0, stream>>>(x, Wq, Wk, Wv, Wo, xb, Wqkv);

    dim3 gq(32, 24);   // 128^2, 768 blocks = 3/CU (proven 39.4 us)
    gemm_bt<128, 128, 1, 1><<<gq, 256, 0, stream>>>(xb, Wqkv, qk, vT, 1024, 2048);

    // R6: 32x32-MFMA attention, in-register S, 32-row q-tiles paired uniformly
    dim3 ga(8, 16, 4); // pair-group x heads x batch
    based_attn32<<<ga, 256, 0, stream>>>(qk, vT, o);

    dim3 go(32, 16);   // o-proj 128x64, 512 blocks = 2/CU (proven R4 win)
    gemm_bt<128, 64, 0, 2><<<go, 256, 0, stream>>>(o, Wob, (void*)out, nullptr, 1024, 1024);
}